// Round 4
// baseline (1194.337 us; speedup 1.0000x reference)
//
#include <hip/hip_runtime.h>
#include <hip/hip_cooperative_groups.h>
#include <cstdint>
#include <cstddef>

namespace cg = cooperative_groups;

#define BPTS    131072
#define D_DIM   128
#define G_GR    128
#define NL      8
#define NSLC    8                  // slices per group -> 1024 blocks
#define GRID    (G_GR * NSLC)      // 1024 = 4 blocks/CU on 256 CUs
#define HBLKS   256                // virtual blocks for hist/scatter phases
#define PPB     (BPTS / HBLKS)     // 512 contiguous points each
#define PERMBUF 256                // max slice len ~142 for B=131072,G=128

// One cooperative kernel: hist -> scatter -> psum -> reduce -> dist -> final,
// separated by grid.sync(). 4 blocks/CU co-resident (launch_bounds 256,4).
__global__ __launch_bounds__(256, 4) void k_all(
    const float4* __restrict__ X4,
    const int*    __restrict__ sub,
    const int*    __restrict__ lab,
    int*          __restrict__ gidx,
    int*          __restrict__ hblk,
    int*          __restrict__ counts,
    int*          __restrict__ offsets,
    float*        __restrict__ countsf,
    int*          __restrict__ perm,
    float*        __restrict__ part,
    float*        __restrict__ centroid,
    float*        __restrict__ dpart,
    float*        __restrict__ out)
{
    cg::grid_group grid = cg::this_grid();
    const int t = threadIdx.x, blk = blockIdx.x;
    const int lane = t & 63, w = t >> 6;

    __shared__ int   ish[G_GR];        // hist counts / scatter cursor
    __shared__ int   tot[G_GR];
    __shared__ int   pbuf[PERMBUF];
    __shared__ float red[4 * 256];
    __shared__ float cen[D_DIM];
    __shared__ float srt[G_GR];
    __shared__ float fred[G_GR];
    __shared__ float coc[D_DIM];

    // ---------------- phase 1: per-block histogram + gidx cache ----------------
    if (blk < HBLKS) {
        if (t < G_GR) ish[t] = 0;
        __syncthreads();
        int b0 = blk * PPB;
        for (int i = t; i < PPB; i += 256) {
            int g = sub[b0 + i] * NL + lab[b0 + i];
            gidx[b0 + i] = g;
            atomicAdd(&ish[g], 1);
        }
        __syncthreads();
        if (t < G_GR) hblk[blk * G_GR + t] = ish[t];
    }
    __threadfence();
    grid.sync();

    // ---------------- phase 2: scatter (prefix recomputed per block) -----------
    if (blk < HBLKS) {
        if (t < G_GR) {
            int tt = 0, mine = 0;
            for (int b = 0; b < HBLKS; ++b) {
                int v = hblk[b * G_GR + t];
                tt += v;
                if (b < blk) mine += v;
            }
            tot[t] = tt;
            ish[t] = mine;            // stash
        }
        __syncthreads();
        if (t < G_GR) {
            int off = 0;
            for (int j = 0; j < t; ++j) off += tot[j];
            ish[t] = off + ish[t];    // cursor seed (deterministic base)
            if (blk == 0) {
                counts[t]  = tot[t];
                offsets[t] = off;
                countsf[t] = 2.0f * (float)tot[t];
            }
        }
        __syncthreads();
        int b0 = blk * PPB;
        for (int i = t; i < PPB; i += 256) {
            int p = b0 + i;
            int g = gidx[p];
            int s = atomicAdd(&ish[g], 1);   // LDS-only cursor
            perm[s] = p;
        }
    }
    __threadfence();
    grid.sync();

    // ---------------- phase 3: psum (block = (g,s) slice) ----------------------
    {
        int g = blk >> 3, s = blk & 7;
        int off = offsets[g], len = counts[g];
        int lo = off + (len * s) / NSLC;
        int hi = off + (len * (s + 1)) / NSLC;
        int slen = hi - lo;
        for (int j = t; j < slen; j += 256) pbuf[j] = perm[lo + j];
        __syncthreads();

        float4 acc = make_float4(0.f, 0.f, 0.f, 0.f);
        for (int i = w * 8; i < slen; i += 32) {
            int idx[8];
#pragma unroll
            for (int u = 0; u < 8; ++u) {
                int j = i + u;
                idx[u] = pbuf[(j < slen) ? j : (slen - 1)];
            }
            float4 x[8];
#pragma unroll
            for (int u = 0; u < 8; ++u) x[u] = X4[(size_t)idx[u] * 64 + lane];
#pragma unroll
            for (int u = 0; u < 8; ++u) {
                if (i + u < slen) {
                    acc.x += x[u].x; acc.y += x[u].y;
                    acc.z += x[u].z; acc.w += x[u].w;
                }
            }
        }
        red[w * 256 + lane * 4 + 0] = acc.x;
        red[w * 256 + lane * 4 + 1] = acc.y;
        red[w * 256 + lane * 4 + 2] = acc.z;
        red[w * 256 + lane * 4 + 3] = acc.w;
        __syncthreads();
        if (t < 128) {   // fold 4 wave copies + the two views
            float v = 0.f;
            for (int r = 0; r < 4; ++r)
                v += red[r * 256 + t] + red[r * 256 + t + 128];
            part[(size_t)blk * 128 + t] = v;
        }
    }
    __threadfence();
    grid.sync();

    // ---------------- phase 4: reduce -> centroid ------------------------------
    if (blk < 64) {
        int i = blk * 256 + t;          // < 16384
        int g = i >> 7, d = i & 127;
        float v = 0.f;
        for (int s2 = 0; s2 < NSLC; ++s2)
            v += part[(size_t)(g * NSLC + s2) * 128 + d];
        int n = counts[g];
        centroid[i] = (n > 0) ? v / (2.0f * (float)n) : 0.f;
    }
    __threadfence();
    grid.sync();

    // ---------------- phase 5: dist (block = (g,s) slice) ----------------------
    {
        int g = blk >> 3, s = blk & 7;
        int off = offsets[g], len = counts[g];
        int lo = off + (len * s) / NSLC;
        int hi = off + (len * (s + 1)) / NSLC;
        int slen = hi - lo;
        for (int j = t; j < slen; j += 256) pbuf[j] = perm[lo + j];
        if (t < D_DIM) cen[t] = centroid[g * D_DIM + t];
        __syncthreads();

        int cd = (lane & 31) * 4;
        float4 c = make_float4(cen[cd], cen[cd + 1], cen[cd + 2], cen[cd + 3]);

        float sacc = 0.f;
        for (int i = w * 8; i < slen; i += 32) {
            int idx[8];
#pragma unroll
            for (int u = 0; u < 8; ++u) {
                int j = i + u;
                idx[u] = pbuf[(j < slen) ? j : (slen - 1)];
            }
            float4 x[8];
#pragma unroll
            for (int u = 0; u < 8; ++u) x[u] = X4[(size_t)idx[u] * 64 + lane];
#pragma unroll
            for (int u = 0; u < 8; ++u) {
                float dx = x[u].x - c.x, dy = x[u].y - c.y;
                float dz = x[u].z - c.z, dw = x[u].w - c.w;
                float d = dx * dx + dy * dy + dz * dz + dw * dw;
#pragma unroll
                for (int m = 1; m <= 16; m <<= 1) d += __shfl_xor(d, m);
                if (i + u < slen) sacc += sqrtf(sqrtf(d));  // sqrt(||x-c||)
            }
        }
        float t2 = sacc + __shfl_xor(sacc, 32);   // fold the two views
        if (lane == 0) red[w] = t2;
        __syncthreads();
        if (t == 0) dpart[blk] = red[0] + red[1] + red[2] + red[3];
    }
    __threadfence();
    grid.sync();

    // ---------------- phase 6: final scalar epilogue (block 0) -----------------
    if (blk == 0) {
        float dens = 0.f, cnt = 0.f;
        if (t < G_GR) {
            float ds = 0.f;
            for (int s2 = 0; s2 < NSLC; ++s2) ds += dpart[t * NSLC + s2];
            cnt  = countsf[t];
            dens = (cnt > 1.f) ? (ds / cnt) / logf(cnt + 10.f) : 0.f;
            fred[t] = dens;
        }
        __syncthreads();
        for (int s2 = 64; s2 > 0; s2 >>= 1) {
            if (t < s2) fred[t] = fmaxf(fred[t], fred[t + s2]);
            __syncthreads();
        }
        float dmax = fred[0];
        __syncthreads();
        if (t < G_GR) {
            if (!(cnt > 1.f)) dens = dmax;
            srt[t] = dens;
        }
        __syncthreads();
        // bitonic sort ascending over 128
        for (int k = 2; k <= G_GR; k <<= 1) {
            for (int j = k >> 1; j > 0; j >>= 1) {
                if (t < G_GR) {
                    int ixj = t ^ j;
                    if (ixj > t) {
                        float a = srt[t], b = srt[ixj];
                        bool up = ((t & k) == 0);
                        if ((a > b) == up) { srt[t] = b; srt[ixj] = a; }
                    }
                }
                __syncthreads();
            }
        }
        double p10 = 0.10 * 127.0, p90 = 0.90 * 127.0;
        int   i10 = (int)p10,           i90 = (int)p90;
        float f10 = (float)(p10 - i10), f90 = (float)(p90 - i90);
        float lo = srt[i10] + f10 * (srt[i10 + 1] - srt[i10]);
        float hi = srt[i90] + f90 * (srt[i90 + 1] - srt[i90]);
        dens = fminf(fmaxf(dens, lo), hi);

        if (t < G_GR) fred[t] = dens;
        __syncthreads();
        for (int s2 = 64; s2 > 0; s2 >>= 1) {
            if (t < s2) fred[t] += fred[t + s2];
            __syncthreads();
        }
        float dmean = fred[0] / 128.f;
        __syncthreads();
        dens = 0.1f * dens / dmean;

        if (t < D_DIM) {
            float cs = 0.f;
            for (int g2 = 0; g2 < G_GR; ++g2) cs += centroid[g2 * D_DIM + t];
            coc[t] = cs / 128.f;
        }
        __syncthreads();
        float sim = 0.f;
        if (t < G_GR) {
            float dot = 0.f;
            for (int d = 0; d < D_DIM; ++d) dot += centroid[t * D_DIM + d] * coc[d];
            sim = expf(dot / dens);
            fred[t] = sim;
        }
        __syncthreads();
        for (int s2 = 64; s2 > 0; s2 >>= 1) {
            if (t < s2) fred[t] = fmaxf(fred[t], fred[t + s2]);
            __syncthreads();
        }
        float smax = fred[0];
        __syncthreads();
        if (t < G_GR) fred[t] = sim - smax;
        __syncthreads();
        for (int s2 = 64; s2 > 0; s2 >>= 1) {
            if (t < s2) fred[t] += fred[t + s2];
            __syncthreads();
        }
        if (t == 0) out[0] = -(fred[0] / 128.f);
    }
}

// ---------------------------------------------------------------------------
extern "C" void kernel_launch(void* const* d_in, const int* in_sizes, int n_in,
                              void* d_out, int out_size, void* d_ws, size_t ws_size,
                              hipStream_t stream) {
    const float4* X4      = (const float4*)d_in[0];
    const int*    subject = (const int*)d_in[1];
    const int*    labels  = (const int*)d_in[2];
    float*        out     = (float*)d_out;
    char*         ws      = (char*)d_ws;

    size_t o = 0;
    int*   gidx     = (int*)(ws + o);   o += (size_t)BPTS * 4;             // 512 KiB
    int*   hblk     = (int*)(ws + o);   o += (size_t)HBLKS * G_GR * 4;     // 128 KiB
    int*   counts   = (int*)(ws + o);   o += 512;
    int*   offsets  = (int*)(ws + o);   o += 512;
    float* countsf  = (float*)(ws + o); o += 512;
    int*   perm     = (int*)(ws + o);   o += (size_t)BPTS * 4;             // 512 KiB
    float* part     = (float*)(ws + o); o += (size_t)GRID * 128 * 4;       // 512 KiB
    float* centroid = (float*)(ws + o); o += (size_t)G_GR * D_DIM * 4;     // 64 KiB
    float* dpart    = (float*)(ws + o); o += (size_t)GRID * 4;             // 4 KiB

    void* args[] = {&X4, &subject, &labels, &gidx, &hblk, &counts, &offsets,
                    &countsf, &perm, &part, &centroid, &dpart, &out};
    hipLaunchCooperativeKernel((void*)k_all, dim3(GRID), dim3(256), args, 0, stream);
}

// Round 5
// 242.834 us; speedup vs baseline: 4.9183x; 4.9183x over previous
//
#include <hip/hip_runtime.h>
#include <cstdint>
#include <cstddef>

#define BPTS    131072
#define D_DIM   128
#define G_GR    128
#define NL      8
#define NSLC    16                 // slices per group -> 2048 heavy blocks
#define PERMBUF 128                // max slice len ~72 (count ~1024±32, /16)
#define NBLK_S  64                 // sort blocks
#define PPB     (BPTS / NBLK_S)    // 2048 contiguous points per sort block

// ---------------------------------------------------------------------------
// k_hist: per-block histogram of group ids -> hblk[blk][128]
// ---------------------------------------------------------------------------
__global__ __launch_bounds__(256) void k_hist(const int* __restrict__ sub,
                                              const int* __restrict__ lab,
                                              int* __restrict__ hblk) {
    __shared__ int h[G_GR];
    int t = threadIdx.x, blk = blockIdx.x;
    if (t < G_GR) h[t] = 0;
    __syncthreads();
    int b0 = blk * PPB;
    for (int i = t; i < PPB; i += 256)
        atomicAdd(&h[sub[b0 + i] * NL + lab[b0 + i]], 1);
    __syncthreads();
    if (t < G_GR) hblk[blk * G_GR + t] = h[t];
}

// ---------------------------------------------------------------------------
// k_scatter: fused prefix (recomputed per block from hblk, deterministic) +
// scatter via per-block LDS cursor. Block 0 publishes counts/offsets/countsf.
// ---------------------------------------------------------------------------
__global__ __launch_bounds__(256) void k_scatter(const int* __restrict__ sub,
                                                 const int* __restrict__ lab,
                                                 const int* __restrict__ hblk,
                                                 int* __restrict__ counts,
                                                 int* __restrict__ offsets,
                                                 float* __restrict__ countsf,
                                                 int* __restrict__ perm) {
    __shared__ int tot[G_GR];
    __shared__ int cur[G_GR];
    int t = threadIdx.x, blk = blockIdx.x;
    if (t < G_GR) {
        int tt = 0, mine = 0;
        for (int b = 0; b < NBLK_S; ++b) {
            int v = hblk[b * G_GR + t];
            tt += v;
            if (b < blk) mine += v;
        }
        tot[t] = tt;
        cur[t] = mine;
    }
    __syncthreads();
    if (t < G_GR) {
        int off = 0;
        for (int j = 0; j < t; ++j) off += tot[j];
        cur[t] += off;
        if (blk == 0) {
            counts[t]  = tot[t];
            offsets[t] = off;
            countsf[t] = 2.0f * (float)tot[t];
        }
    }
    __syncthreads();
    int b0 = blk * PPB;
    for (int i = t; i < PPB; i += 256) {
        int p = b0 + i;
        int g = sub[p] * NL + lab[p];
        int s = atomicAdd(&cur[g], 1);   // LDS-only cursor
        perm[s] = p;
    }
}

// ---------------------------------------------------------------------------
// k_psum: block (g,s) sums its slice of group g. Wave-per-point, batched
// unroll-8 float4 loads, register accumulate, zero atomics.
// ---------------------------------------------------------------------------
__global__ __launch_bounds__(256) void k_psum(const float4* __restrict__ X4,
                                              const int* __restrict__ perm,
                                              const int* __restrict__ offsets,
                                              const int* __restrict__ counts,
                                              float* __restrict__ part) {
    __shared__ int   pbuf[PERMBUF];
    __shared__ float red[4 * 256];
    int g = blockIdx.x >> 4, s = blockIdx.x & 15;
    int off = offsets[g], len = counts[g];
    int lo = off + (len * s) / NSLC;
    int hi = off + (len * (s + 1)) / NSLC;
    int slen = hi - lo;
    int t = threadIdx.x, lane = t & 63, w = t >> 6;

    for (int j = t; j < slen; j += 256) pbuf[j] = perm[lo + j];
    __syncthreads();

    float4 acc = make_float4(0.f, 0.f, 0.f, 0.f);
    for (int i = w * 8; i < slen; i += 32) {
        int idx[8];
#pragma unroll
        for (int u = 0; u < 8; ++u) {
            int j = i + u;
            idx[u] = pbuf[(j < slen) ? j : (slen - 1)];
        }
        float4 x[8];
#pragma unroll
        for (int u = 0; u < 8; ++u) x[u] = X4[(size_t)idx[u] * 64 + lane];
#pragma unroll
        for (int u = 0; u < 8; ++u) {
            if (i + u < slen) {
                acc.x += x[u].x; acc.y += x[u].y;
                acc.z += x[u].z; acc.w += x[u].w;
            }
        }
    }
    red[w * 256 + lane * 4 + 0] = acc.x;
    red[w * 256 + lane * 4 + 1] = acc.y;
    red[w * 256 + lane * 4 + 2] = acc.z;
    red[w * 256 + lane * 4 + 3] = acc.w;
    __syncthreads();
    if (t < 128) {                        // fold 4 wave copies + the two views
        float v = 0.f;
        for (int r = 0; r < 4; ++r)
            v += red[r * 256 + t] + red[r * 256 + t + 128];
        part[(size_t)blockIdx.x * 128 + t] = v;
    }
}

// ---------------------------------------------------------------------------
// k_dist: fused centroid reduce (deterministic, redundant per slice; slice 0
// publishes centroid for k_final) + per-point ||x-c|| via 32-lane shfl
// butterfly; accumulate sqrt(||x-c||) per block.
// ---------------------------------------------------------------------------
__global__ __launch_bounds__(256) void k_dist(const float4* __restrict__ X4,
                                              const int* __restrict__ perm,
                                              const int* __restrict__ offsets,
                                              const int* __restrict__ counts,
                                              const float* __restrict__ part,
                                              float* __restrict__ centroid,
                                              float* __restrict__ dpart) {
    __shared__ int   pbuf[PERMBUF];
    __shared__ float cen[D_DIM];
    __shared__ float wsum[4];
    int g = blockIdx.x >> 4, s = blockIdx.x & 15;
    int off = offsets[g], len = counts[g];
    int lo = off + (len * s) / NSLC;
    int hi = off + (len * (s + 1)) / NSLC;
    int slen = hi - lo;
    int t = threadIdx.x, lane = t & 63, w = t >> 6;

    if (t < D_DIM) {                      // fused k_reduce
        float v = 0.f;
        for (int s2 = 0; s2 < NSLC; ++s2)
            v += part[(size_t)(g * NSLC + s2) * 128 + t];
        float c = (len > 0) ? v / (2.0f * (float)len) : 0.f;
        cen[t] = c;
        if (s == 0) centroid[g * D_DIM + t] = c;
    }
    for (int j = t; j < slen; j += 256) pbuf[j] = perm[lo + j];
    __syncthreads();

    int cd = (lane & 31) * 4;
    float4 c = make_float4(cen[cd], cen[cd + 1], cen[cd + 2], cen[cd + 3]);

    float sacc = 0.f;
    for (int i = w * 8; i < slen; i += 32) {
        int idx[8];
#pragma unroll
        for (int u = 0; u < 8; ++u) {
            int j = i + u;
            idx[u] = pbuf[(j < slen) ? j : (slen - 1)];
        }
        float4 x[8];
#pragma unroll
        for (int u = 0; u < 8; ++u) x[u] = X4[(size_t)idx[u] * 64 + lane];
#pragma unroll
        for (int u = 0; u < 8; ++u) {
            float dx = x[u].x - c.x, dy = x[u].y - c.y;
            float dz = x[u].z - c.z, dw = x[u].w - c.w;
            float d = dx * dx + dy * dy + dz * dz + dw * dw;
#pragma unroll
            for (int m = 1; m <= 16; m <<= 1) d += __shfl_xor(d, m);
            if (i + u < slen) sacc += sqrtf(sqrtf(d));   // sqrt(||x-c||)
        }
    }
    float t2 = sacc + __shfl_xor(sacc, 32);   // fold the two views
    if (lane == 0) wsum[w] = t2;
    __syncthreads();
    if (t == 0) dpart[blockIdx.x] = wsum[0] + wsum[1] + wsum[2] + wsum[3];
}

// ---------------------------------------------------------------------------
// k_final: single block, 128 threads (thread t = group t).
// ---------------------------------------------------------------------------
__global__ __launch_bounds__(128) void k_final(const float* __restrict__ dpart,
                                               const float* __restrict__ countsf,
                                               const float* __restrict__ centroid,
                                               float* __restrict__ out) {
    __shared__ float srt[G_GR];
    __shared__ float red[G_GR];
    __shared__ float coc[D_DIM];
    int t = threadIdx.x;

    float ds = 0.f;
    for (int s = 0; s < NSLC; ++s) ds += dpart[t * NSLC + s];
    float cnt  = countsf[t];
    float dens = (cnt > 1.f) ? (ds / cnt) / logf(cnt + 10.f) : 0.f;

    red[t] = dens;
    __syncthreads();
    for (int s = 64; s > 0; s >>= 1) {
        if (t < s) red[t] = fmaxf(red[t], red[t + s]);
        __syncthreads();
    }
    float dmax = red[0];
    __syncthreads();
    if (!(cnt > 1.f)) dens = dmax;

    // bitonic sort ascending
    srt[t] = dens;
    __syncthreads();
    for (int k = 2; k <= G_GR; k <<= 1) {
        for (int j = k >> 1; j > 0; j >>= 1) {
            int ixj = t ^ j;
            if (ixj > t) {
                float a = srt[t], b = srt[ixj];
                bool up = ((t & k) == 0);
                if ((a > b) == up) { srt[t] = b; srt[ixj] = a; }
            }
            __syncthreads();
        }
    }
    double p10 = 0.10 * 127.0, p90 = 0.90 * 127.0;
    int   i10 = (int)p10,           i90 = (int)p90;
    float f10 = (float)(p10 - i10), f90 = (float)(p90 - i90);
    float lo = srt[i10] + f10 * (srt[i10 + 1] - srt[i10]);
    float hi = srt[i90] + f90 * (srt[i90 + 1] - srt[i90]);
    dens = fminf(fmaxf(dens, lo), hi);

    red[t] = dens;
    __syncthreads();
    for (int s = 64; s > 0; s >>= 1) {
        if (t < s) red[t] += red[t + s];
        __syncthreads();
    }
    float dmean = red[0] / 128.f;
    __syncthreads();
    dens = 0.1f * dens / dmean;

    float cs = 0.f;
    for (int g = 0; g < G_GR; ++g) cs += centroid[g * D_DIM + t];
    coc[t] = cs / 128.f;
    __syncthreads();

    float dot = 0.f;
    for (int d = 0; d < D_DIM; ++d) dot += centroid[t * D_DIM + d] * coc[d];
    float sim = expf(dot / dens);

    red[t] = sim;
    __syncthreads();
    for (int s = 64; s > 0; s >>= 1) {
        if (t < s) red[t] = fmaxf(red[t], red[t + s]);
        __syncthreads();
    }
    float smax = red[0];
    __syncthreads();
    red[t] = sim - smax;
    __syncthreads();
    for (int s = 64; s > 0; s >>= 1) {
        if (t < s) red[t] += red[t + s];
        __syncthreads();
    }
    if (t == 0) out[0] = -(red[0] / 128.f);
}

// ---------------------------------------------------------------------------
extern "C" void kernel_launch(void* const* d_in, const int* in_sizes, int n_in,
                              void* d_out, int out_size, void* d_ws, size_t ws_size,
                              hipStream_t stream) {
    const float4* X4      = (const float4*)d_in[0];
    const int*    subject = (const int*)d_in[1];
    const int*    labels  = (const int*)d_in[2];
    float*        out     = (float*)d_out;
    char*         ws      = (char*)d_ws;

    size_t o = 0;
    int*   hblk     = (int*)(ws + o);   o += (size_t)NBLK_S * G_GR * 4;     // 32 KiB
    int*   counts   = (int*)(ws + o);   o += 512;
    int*   offsets  = (int*)(ws + o);   o += 512;
    float* countsf  = (float*)(ws + o); o += 512;
    int*   perm     = (int*)(ws + o);   o += (size_t)BPTS * 4;              // 512 KiB
    float* part     = (float*)(ws + o); o += (size_t)G_GR * NSLC * 128 * 4; // 1 MiB
    float* centroid = (float*)(ws + o); o += (size_t)G_GR * D_DIM * 4;      // 64 KiB
    float* dpart    = (float*)(ws + o); o += (size_t)G_GR * NSLC * 4;       // 8 KiB

    k_hist   <<<NBLK_S, 256, 0, stream>>>(subject, labels, hblk);
    k_scatter<<<NBLK_S, 256, 0, stream>>>(subject, labels, hblk, counts, offsets, countsf, perm);
    k_psum   <<<G_GR * NSLC, 256, 0, stream>>>(X4, perm, offsets, counts, part);
    k_dist   <<<G_GR * NSLC, 256, 0, stream>>>(X4, perm, offsets, counts, part, centroid, dpart);
    k_final  <<<1, 128, 0, stream>>>(dpart, countsf, centroid, out);
}